// Round 7
// baseline (131.526 us; speedup 1.0000x reference)
//
#include <hip/hip_runtime.h>
#include <hip/hip_fp16.h>

#define NP    128   // planets per batch
#define NH    64    // hidden dim
#define ITERS 4     // batches per wave
#define WPB   4     // waves per block

typedef __attribute__((ext_vector_type(8))) _Float16 f16x8;   // K32 MFMA A/B operand
typedef __attribute__((ext_vector_type(4))) _Float16 f16x4;   // K16 MFMA A/B operand
typedef __attribute__((ext_vector_type(2))) __fp16  hf16x2;   // cvt_pkrtz return type
typedef __attribute__((ext_vector_type(4))) float f32x4;

union FragK16 { f16x4 v; unsigned int u[2]; };
union FragK32 { f16x8 v; unsigned int u[4]; };

__device__ __forceinline__ unsigned int pack_pkrtz(float a, float b) {
    hf16x2 t = __builtin_amdgcn_cvt_pkrtz(a, b);
    return __builtin_bit_cast(unsigned int, t);
}

// packed f16 relu (v_pk_max_f16). relu(rtz(x)) == rtz(relu(x)).
__device__ __forceinline__ unsigned int relu2_pk(unsigned int u) {
    hf16x2 h = __builtin_bit_cast(hf16x2, u);
    h = __builtin_elementwise_max(h, (hf16x2)(__fp16)0.f);
    return __builtin_bit_cast(unsigned int, h);
}

// 4 independent waves/block, ITERS batches each, register-resident, NO LDS.
//
// Model locked in by R1-R6: duration = MFMA-pipe-work / MfmaUtil, and
// MfmaUtil (~50%) tracks RESIDENT WAVES, which are bound by TRUE register
// use (VGPR+AGPR unified — rocprof's VGPR_Count=60 hides the AGPR side;
// R1 is ~165 true = 3 waves/SIMD). R6 proved independent chains do NOT
// raise MfmaUtil — dependencies were never the cap.
//
// THIS VERSION attacks both terms at once:
//  * reduction MFMA (ones@mf) REMOVED from the MFMA pipe (-310 cy/batch,
//    -17% MFMA work): in the swapped layout msg rows are planets, so the
//    per-lane sum over its 4 C-regs + f32 accumulate (vsum[np]) does the
//    in-q-group planet sum on the VALU pipe; one shfl_xor(16)+shfl_xor(32)
//    pass per np at batch end finishes the cross-q sum. Also skips the
//    msg->f16 rounding (packM) — slightly MORE accurate than before.
//  * frees redD(16, AGPR) + mf(8) + onesA(2) true regs, adds vsum(4):
//    ~-20 true regs -> leaner live set; __launch_bounds__(256,3) caps
//    alloc at ~170 so the allocator must keep >=3 waves/SIMD resident.
//
// Layer structure (unchanged since R1):
//   layer1 16x16x16 (b1 folded as constant-1 feature k=4);
//   sigma(32kk+8q+j)=16*(2kk+(j>>2))+4q+(j&3) makes the K32 layer2 A-operand
//   a pure register concat of layer1 C-fragments (written directly in place);
//   layer2 operands swapped so PLANETS sit on the (q,reg) axis of the C tile.
__global__ void __launch_bounds__(256, 3) gnn_wave(
    const float* __restrict__ planet_xy,  // [B][P][2]
    const float* __restrict__ planet_m,   // [P]
    const float* __restrict__ ast_xy,     // [B][2]
    const float* __restrict__ W1,         // [4][64]
    const float* __restrict__ b1,         // [64]
    const float* __restrict__ W2,         // [64][64]
    const float* __restrict__ b2,         // [64]
    float* __restrict__ out)              // [B][64]
{
    const int tid  = threadIdx.x;
    const int wv   = tid >> 6;
    const int lane = tid & 63;
    const int q    = lane >> 4;
    const int lm   = lane & 15;
    const bool q0  = (q == 0);
    const bool q1  = (q == 1);

    // ---- layer1 A-frags (16x16x16), b1 folded as constant-1 feature k=4 ----
    FragK16 w1f[4];
    #pragma unroll
    for (int mt = 0; mt < 4; mt++) {
        const int m = 16 * mt + lm;
        float wa = W1[0 * NH + m], wb = W1[1 * NH + m];
        float wc = W1[2 * NH + m], wd = W1[3 * NH + m];
        float be = b1[m];
        w1f[mt].u[0] = q0 ? pack_pkrtz(wa, wb) : (q1 ? pack_pkrtz(be, 0.f) : 0u);
        w1f[mt].u[1] = q0 ? pack_pkrtz(wc, wd) : 0u;
    }

    // ---- layer2 B-frags (16x16x32), sigma-permuted W2 rows ----
    FragK32 w2b[4][2];   // [np][kk]
    #pragma unroll
    for (int np = 0; np < 4; np++)
        #pragma unroll
        for (int kk = 0; kk < 2; kk++) {
            const int n = 16 * np + lm;
            const int k0 = 32 * kk + 4 * q;        // j>>2 == 0 rows
            const int k1 = 32 * kk + 16 + 4 * q;   // j>>2 == 1 rows
            w2b[np][kk].u[0] = pack_pkrtz(W2[(k0 + 0) * NH + n], W2[(k0 + 1) * NH + n]);
            w2b[np][kk].u[1] = pack_pkrtz(W2[(k0 + 2) * NH + n], W2[(k0 + 3) * NH + n]);
            w2b[np][kk].u[2] = pack_pkrtz(W2[(k1 + 0) * NH + n], W2[(k1 + 1) * NH + n]);
            w2b[np][kk].u[3] = pack_pkrtz(W2[(k1 + 2) * NH + n], W2[(k1 + 3) * NH + n]);
        }

    // b2 as layer2 C-init: output rows are planets, cols n'=16np+lm -> broadcast
    f32x4 b2f[4];
    #pragma unroll
    for (int np = 0; np < 4; np++) {
        const float bv = b2[16 * np + lm];
        b2f[np] = (f32x4){bv, bv, bv, bv};
    }

    // batch-invariant planet masses (planet 16*i + lm)
    float pmv[8];
    #pragma unroll
    for (int i = 0; i < 8; i++)
        pmv[i] = planet_m[16 * i + lm];

    const unsigned int bf0_const = q1 ? pack_pkrtz(1.f, 0.f) : 0u;
    const f32x4 zf = (f32x4){0.f, 0.f, 0.f, 0.f};

    int b = (blockIdx.x * WPB + wv) * ITERS;

    #pragma unroll 1
    for (int it = 0; it < ITERS; ++it, ++b) {
        const float2 axy = *(const float2*)&ast_xy[2 * b];
        float2 pxy[8];
        #pragma unroll
        for (int i = 0; i < 8; i++)
            pxy[i] = *(const float2*)&planet_xy[((size_t)b * NP + 16 * i + lm) * 2];

        // per-lane planet-sum accumulators: vsum[np] sums msg over this
        // lane's q-group rows (p = 16mi + 4q + r), f32, all in VGPRs.
        f32x4 vsum = zf;

        #pragma unroll
        for (int mi = 0; mi < 8; ++mi) {
            // feats B-frag for planets 16mi..16mi+15
            float dx = pxy[mi].x - axy.x, dy = pxy[mi].y - axy.y;
            float inv = __builtin_amdgcn_rsqf(fmaf(dx, dx, fmaf(dy, dy, 1e-6f)));
            FragK16 bf;
            bf.u[0] = q0 ? pack_pkrtz(dx, dy)        : bf0_const;
            bf.u[1] = q0 ? pack_pkrtz(inv, pmv[mi])  : 0u;

            // layer1: relu'd h packs written DIRECTLY into sigma-ordered K32
            // A-frag slots: hA[mt>>1].u[2*(mt&1)+{0,1}]
            FragK32 hA[2];
            #pragma unroll
            for (int mt = 0; mt < 4; mt++) {
                f32x4 c = __builtin_amdgcn_mfma_f32_16x16x16f16(w1f[mt].v, bf.v, zf, 0, 0, 0);
                hA[mt >> 1].u[2 * (mt & 1) + 0] = relu2_pk(pack_pkrtz(c[0], c[1]));
                hA[mt >> 1].u[2 * (mt & 1) + 1] = relu2_pk(pack_pkrtz(c[2], c[3]));
            }

            // layer2: msg tile [p=4q+r][n'=16np+lm], full-rate K32; then
            // relu + in-register planet sum on the VALU pipe (f32).
            #pragma unroll
            for (int np = 0; np < 4; np++) {
                f32x4 acc = __builtin_amdgcn_mfma_f32_16x16x32_f16(hA[0].v, w2b[np][0].v, b2f[np], 0, 0, 0);
                acc = __builtin_amdgcn_mfma_f32_16x16x32_f16(hA[1].v, w2b[np][1].v, acc, 0, 0, 0);
                acc = __builtin_elementwise_max(acc, zf);            // relu
                vsum[np] += (acc[0] + acc[1]) + (acc[2] + acc[3]);   // sum 4 planets
            }
        }

        // cross-q planet sum: lanes (q,lm) hold partials over rows 4q+r;
        // butterfly over lane^16 / lane^32 completes the 128-planet sum.
        #pragma unroll
        for (int np = 0; np < 4; np++) {
            float s = vsum[np];
            s += __shfl_xor(s, 16, 64);
            s += __shfl_xor(s, 32, 64);
            vsum[np] = s;
        }

        // lane 16q+lm needs n' = lane -> select np == q; coalesced b32 store
        float v = q0 ? vsum[0]
                : q1 ? vsum[1]
                : (q == 2) ? vsum[2] : vsum[3];
        out[(size_t)b * NH + lane] = v;
    }
}

extern "C" void kernel_launch(void* const* d_in, const int* in_sizes, int n_in,
                              void* d_out, int out_size, void* d_ws, size_t ws_size,
                              hipStream_t stream) {
    const float* planet_xy = (const float*)d_in[0];
    const float* planet_m  = (const float*)d_in[1];
    const float* ast_xy    = (const float*)d_in[2];
    const float* W1        = (const float*)d_in[3];
    const float* b1        = (const float*)d_in[4];
    const float* W2        = (const float*)d_in[5];
    const float* b2        = (const float*)d_in[6];
    float* outp            = (float*)d_out;

    const int B = in_sizes[2] / 2;   // ast_xy is [B][2]
    const int batches_per_block = WPB * ITERS;
    const int grid = (B + batches_per_block - 1) / batches_per_block;

    gnn_wave<<<grid, 256, 0, stream>>>(planet_xy, planet_m, ast_xy, W1, b1, W2, b2, outp);
}

// Round 8
// 130.032 us; speedup vs baseline: 1.0115x; 1.0115x over previous
//
#include <hip/hip_runtime.h>
#include <hip/hip_fp16.h>

#define NP    128   // planets per batch
#define NH    64    // hidden dim
#define ITERS 4     // batches per wave
#define WPB   4     // waves per block

typedef __attribute__((ext_vector_type(8))) _Float16 f16x8;   // K32 MFMA A/B operand
typedef __attribute__((ext_vector_type(4))) _Float16 f16x4;   // K16 MFMA A/B operand
typedef __attribute__((ext_vector_type(2))) __fp16  hf16x2;   // cvt_pkrtz return type
typedef __attribute__((ext_vector_type(4))) float f32x4;

union FragK16 { f16x4 v; unsigned int u[2]; };
union FragK32 { f16x8 v; unsigned int u[4]; };

__device__ __forceinline__ unsigned int pack_pkrtz(float a, float b) {
    hf16x2 t = __builtin_amdgcn_cvt_pkrtz(a, b);
    return __builtin_bit_cast(unsigned int, t);
}

// packed f16 relu (v_pk_max_f16). relu(rtz(x)) == rtz(relu(x)).
__device__ __forceinline__ unsigned int relu2_pk(unsigned int u) {
    hf16x2 h = __builtin_bit_cast(hf16x2, u);
    h = __builtin_elementwise_max(h, (hf16x2)(__fp16)0.f);
    return __builtin_bit_cast(unsigned int, h);
}

// 4 waves/block, ITERS batches each, register-resident, NO LDS.
//
// R1-R7 model: duration ~= MFMA-busy + VALU-busy (+dead time below 3
// waves/SIMD). VALU-busy is ~2x what the source requires: the excess is
// v_accvgpr_read/write shuttle — MFMA C/D sit in AGPRs, every pack/max/
// C-init crosses the file (~64 moves/mi). rocprof's VGPR_Count (60) hides
// the ~100 AGPRs; true alloc ~160 caps residency at 3 waves/SIMD (512-reg
// pool, m69 tiers).
//
// THIS VERSION: __launch_bounds__(256,4) -> 128-TOTAL-reg budget, forcing
// pure-VGPR MFMA form (no AGPR split => no shuttle) AND a 4th resident
// wave. Register diet to make 128 feasible (~105 peak live):
//  * b2f(16) -> nb2s(4): relu(z+b2) = max(z,-b2)+b2; the per-planet max
//    uses -b2, and the +128*b2 constant is folded into the epilogue fma.
//  * pmv(8) -> pmh(4): masses pre-packed to f16 pairs, OR'd into the
//    inv-pack (2 extra VALU/mi; rounding identical to pack_pkrtz of f32).
//  * planet reduction on VALU (vsum, 4 regs) instead of MFMA redD (16):
//    R7 showed its cost was mostly shuttle, which this version eliminates.
//
// Layer structure (unchanged since R1):
//   layer1 16x16x16 (b1 folded as constant-1 feature k=4);
//   sigma(32kk+8q+j)=16*(2kk+(j>>2))+4q+(j&3) makes the K32 layer2 A-operand
//   a pure register concat of layer1 C-fragments (written directly in place);
//   layer2 operands swapped so PLANETS sit on the (q,reg) axis of the C tile;
//   cross-q planet sum via shfl_xor(16)+shfl_xor(32) at batch end.
__global__ void __launch_bounds__(256, 4) gnn_wave(
    const float* __restrict__ planet_xy,  // [B][P][2]
    const float* __restrict__ planet_m,   // [P]
    const float* __restrict__ ast_xy,     // [B][2]
    const float* __restrict__ W1,         // [4][64]
    const float* __restrict__ b1,         // [64]
    const float* __restrict__ W2,         // [64][64]
    const float* __restrict__ b2,         // [64]
    float* __restrict__ out)              // [B][64]
{
    const int tid  = threadIdx.x;
    const int wv   = tid >> 6;
    const int lane = tid & 63;
    const int q    = lane >> 4;
    const int lm   = lane & 15;
    const bool q0  = (q == 0);
    const bool q1  = (q == 1);

    // ---- layer1 A-frags (16x16x16), b1 folded as constant-1 feature k=4 ----
    FragK16 w1f[4];
    #pragma unroll
    for (int mt = 0; mt < 4; mt++) {
        const int m = 16 * mt + lm;
        float wa = W1[0 * NH + m], wb = W1[1 * NH + m];
        float wc = W1[2 * NH + m], wd = W1[3 * NH + m];
        float be = b1[m];
        w1f[mt].u[0] = q0 ? pack_pkrtz(wa, wb) : (q1 ? pack_pkrtz(be, 0.f) : 0u);
        w1f[mt].u[1] = q0 ? pack_pkrtz(wc, wd) : 0u;
    }

    // ---- layer2 B-frags (16x16x32), sigma-permuted W2 rows ----
    FragK32 w2b[4][2];   // [np][kk]
    #pragma unroll
    for (int np = 0; np < 4; np++)
        #pragma unroll
        for (int kk = 0; kk < 2; kk++) {
            const int n = 16 * np + lm;
            const int k0 = 32 * kk + 4 * q;        // j>>2 == 0 rows
            const int k1 = 32 * kk + 16 + 4 * q;   // j>>2 == 1 rows
            w2b[np][kk].u[0] = pack_pkrtz(W2[(k0 + 0) * NH + n], W2[(k0 + 1) * NH + n]);
            w2b[np][kk].u[1] = pack_pkrtz(W2[(k0 + 2) * NH + n], W2[(k0 + 3) * NH + n]);
            w2b[np][kk].u[2] = pack_pkrtz(W2[(k1 + 0) * NH + n], W2[(k1 + 1) * NH + n]);
            w2b[np][kk].u[3] = pack_pkrtz(W2[(k1 + 2) * NH + n], W2[(k1 + 3) * NH + n]);
        }

    // negated b2 (4 scalars/lane): relu(z+b2) = max(z, -b2) + b2
    float nb2s[4];
    #pragma unroll
    for (int np = 0; np < 4; np++)
        nb2s[np] = -b2[16 * np + lm];

    // masses packed to f16 pairs: pmh[i] = (m[32i+lm] lo, m[32i+16+lm] hi)
    unsigned int pmh[4];
    #pragma unroll
    for (int i = 0; i < 4; i++)
        pmh[i] = pack_pkrtz(planet_m[32 * i + lm], planet_m[32 * i + 16 + lm]);

    const unsigned int bf0_const = q1 ? pack_pkrtz(1.f, 0.f) : 0u;
    const f32x4 zf = (f32x4){0.f, 0.f, 0.f, 0.f};

    int b = (blockIdx.x * WPB + wv) * ITERS;

    #pragma unroll 1
    for (int it = 0; it < ITERS; ++it, ++b) {
        const float2 axy = *(const float2*)&ast_xy[2 * b];
        float2 pxy[8];
        #pragma unroll
        for (int i = 0; i < 8; i++)
            pxy[i] = *(const float2*)&planet_xy[((size_t)b * NP + 16 * i + lm) * 2];

        // per-lane planet-sum accumulators (rows p = 16mi + 4q + r)
        f32x4 vsum = zf;

        #pragma unroll
        for (int mi = 0; mi < 8; ++mi) {
            // feats B-frag for planets 16mi..16mi+15
            float dx = pxy[mi].x - axy.x, dy = pxy[mi].y - axy.y;
            float inv = __builtin_amdgcn_rsqf(fmaf(dx, dx, fmaf(dy, dy, 1e-6f)));
            unsigned int invp = pack_pkrtz(inv, 0.f);            // [inv, 0]
            unsigned int pmsel = (mi & 1)
                ? ((pmh[mi >> 1] & 0xFFFF0000u) | invp)          // [inv, m_odd]
                : ((pmh[mi >> 1] << 16) | invp);                 // [inv, m_even]
            FragK16 bf;
            bf.u[0] = q0 ? pack_pkrtz(dx, dy) : bf0_const;
            bf.u[1] = q0 ? pmsel : 0u;

            // layer1: relu'd h packs written DIRECTLY into sigma-ordered K32
            // A-frag slots: hA[mt>>1].u[2*(mt&1)+{0,1}]
            FragK32 hA[2];
            #pragma unroll
            for (int mt = 0; mt < 4; mt++) {
                f32x4 c = __builtin_amdgcn_mfma_f32_16x16x16f16(w1f[mt].v, bf.v, zf, 0, 0, 0);
                hA[mt >> 1].u[2 * (mt & 1) + 0] = relu2_pk(pack_pkrtz(c[0], c[1]));
                hA[mt >> 1].u[2 * (mt & 1) + 1] = relu2_pk(pack_pkrtz(c[2], c[3]));
            }

            // layer2: msg tile [p=4q+r][n'=16np+lm], full-rate K32, zf C-init;
            // relu-with-bias via max(z,-b2) (the +b2 is folded into epilogue);
            // planet sum in f32 on the VALU pipe.
            #pragma unroll
            for (int np = 0; np < 4; np++) {
                f32x4 acc = __builtin_amdgcn_mfma_f32_16x16x32_f16(hA[0].v, w2b[np][0].v, zf, 0, 0, 0);
                acc = __builtin_amdgcn_mfma_f32_16x16x32_f16(hA[1].v, w2b[np][1].v, acc, 0, 0, 0);
                const float nb = nb2s[np];
                float r0 = fmaxf(acc[0], nb), r1 = fmaxf(acc[1], nb);
                float r2 = fmaxf(acc[2], nb), r3 = fmaxf(acc[3], nb);
                vsum[np] += (r0 + r1) + (r2 + r3);
            }
        }

        // cross-q planet sum: butterfly over lane^16 / lane^32
        #pragma unroll
        for (int np = 0; np < 4; np++) {
            float s = vsum[np];
            s += __shfl_xor(s, 16, 64);
            s += __shfl_xor(s, 32, 64);
            vsum[np] = s;
        }

        // lane 16q+lm needs n' = lane -> select np == q, then add back the
        // deferred 128 * b2[lane] (= -128 * nb2 selected at np==q).
        float vs = q0 ? vsum[0]
                 : q1 ? vsum[1]
                 : (q == 2) ? vsum[2] : vsum[3];
        float nb = q0 ? nb2s[0]
                 : q1 ? nb2s[1]
                 : (q == 2) ? nb2s[2] : nb2s[3];
        out[(size_t)b * NH + lane] = fmaf(-128.f, nb, vs);
    }
}

extern "C" void kernel_launch(void* const* d_in, const int* in_sizes, int n_in,
                              void* d_out, int out_size, void* d_ws, size_t ws_size,
                              hipStream_t stream) {
    const float* planet_xy = (const float*)d_in[0];
    const float* planet_m  = (const float*)d_in[1];
    const float* ast_xy    = (const float*)d_in[2];
    const float* W1        = (const float*)d_in[3];
    const float* b1        = (const float*)d_in[4];
    const float* W2        = (const float*)d_in[5];
    const float* b2        = (const float*)d_in[6];
    float* outp            = (float*)d_out;

    const int B = in_sizes[2] / 2;   // ast_xy is [B][2]
    const int batches_per_block = WPB * ITERS;
    const int grid = (B + batches_per_block - 1) / batches_per_block;

    gnn_wave<<<grid, 256, 0, stream>>>(planet_xy, planet_m, ast_xy, W1, b1, W2, b2, outp);
}

// Round 9
// 122.237 us; speedup vs baseline: 1.0760x; 1.0638x over previous
//
#include <hip/hip_runtime.h>
#include <hip/hip_fp16.h>

#define NP    128   // planets per batch
#define NH    64    // hidden dim
#define ITERS 4     // batches per wave
#define WPB   4     // waves per block

typedef __attribute__((ext_vector_type(8))) _Float16 f16x8;   // K32 MFMA A/B operand
typedef __attribute__((ext_vector_type(4))) _Float16 f16x4;   // K16 MFMA A/B operand
typedef __attribute__((ext_vector_type(2))) __fp16  hf16x2;   // cvt_pkrtz return type
typedef __attribute__((ext_vector_type(4))) float f32x4;

union FragK16 { f16x4 v; unsigned int u[2]; };
union FragK32 { f16x8 v; unsigned int u[4]; };

__device__ __forceinline__ unsigned int pack_pkrtz(float a, float b) {
    hf16x2 t = __builtin_amdgcn_cvt_pkrtz(a, b);
    return __builtin_bit_cast(unsigned int, t);
}

// packed f16 relu (v_pk_max_f16). relu(rtz(x)) == rtz(relu(x)).
__device__ __forceinline__ unsigned int relu2_pk(unsigned int u) {
    hf16x2 h = __builtin_bit_cast(hf16x2, u);
    h = __builtin_elementwise_max(h, (hf16x2)(__fp16)0.f);
    return __builtin_bit_cast(unsigned int, h);
}

// R1 structure (best measured: 52.6us/dispatch) + two register-free changes.
//
// Cross-round law (R1/R6/R7/R8): duration ~= MFMA-busy + VALU-busy — the two
// pipes NEVER overlap, at any occupancy, even with independent chains (R6).
// Mechanism: co-resident waves are PHASE-LOCKED. They launch together and
// re-synchronize at every batch boundary (all stall on the same vmcnt for the
// 9 batch-start loads, equal memory latency -> lock-step exit), so their VALU
// phases coincide and their MFMA phases coincide: the SIMD alternates pipes.
//
//  * WAVE PHASE-STAGGER: one-time s_sleep ramp at entry, 0/192/384/576 cy by
//    (blockIdx^blockIdx>>8)+wv — about half an mi-iteration (~480cy) between
//    adjacent co-resident waves. The batch-boundary stall preserves stagger
//    (FIFO through equal-latency memory), so anti-phase persists. 0 VGPR.
//  * readfirstlane-UNIFORM ADDRESSING: b is wave-uniform but tid-derived, so
//    the compiler emitted per-lane 64-bit address math; forcing it scalar
//    moves batch-base arithmetic to SALU and frees a couple of VGPRs.
//
// Layer structure (unchanged since R1):
//   layer1 16x16x16 (b1 folded as constant-1 feature k=4);
//   sigma(32kk+8q+j)=16*(2kk+(j>>2))+4q+(j&3) makes the K32 layer2 A-operand
//   a pure register concat of layer1 C-fragments (written directly in place);
//   layer2 operands swapped so PLANETS sit on the (q,reg) axis; the relu'd
//   msg tile packed to f16 is directly a 16x16x16 B-frag and the 128-planet
//   reduction is 8 accumulating MFMAs against an all-ones A. No LDS.
__global__ void __launch_bounds__(256, 2) gnn_wave(
    const float* __restrict__ planet_xy,  // [B][P][2]
    const float* __restrict__ planet_m,   // [P]
    const float* __restrict__ ast_xy,     // [B][2]
    const float* __restrict__ W1,         // [4][64]
    const float* __restrict__ b1,         // [64]
    const float* __restrict__ W2,         // [64][64]
    const float* __restrict__ b2,         // [64]
    float* __restrict__ out)              // [B][64]
{
    const int tid  = threadIdx.x;
    const int wv   = tid >> 6;
    const int lane = tid & 63;
    const int q    = lane >> 4;
    const int lm   = lane & 15;
    const bool q0  = (q == 0);
    const bool q1  = (q == 1);

    // ---- wave phase-stagger: desynchronize co-resident waves ----
    {
        const int stag = __builtin_amdgcn_readfirstlane(
            (((int)blockIdx.x ^ ((int)blockIdx.x >> 8)) + wv) & 3);
        for (int i = 0; i < stag; ++i)
            asm volatile("s_sleep 3");   // ~192 cy each -> 0/192/384/576
    }

    // ---- layer1 A-frags (16x16x16), b1 folded as constant-1 feature k=4 ----
    FragK16 w1f[4];
    #pragma unroll
    for (int mt = 0; mt < 4; mt++) {
        const int m = 16 * mt + lm;
        float wa = W1[0 * NH + m], wb = W1[1 * NH + m];
        float wc = W1[2 * NH + m], wd = W1[3 * NH + m];
        float be = b1[m];
        w1f[mt].u[0] = q0 ? pack_pkrtz(wa, wb) : (q1 ? pack_pkrtz(be, 0.f) : 0u);
        w1f[mt].u[1] = q0 ? pack_pkrtz(wc, wd) : 0u;
    }

    // ---- layer2 B-frags (16x16x32), sigma-permuted W2 rows ----
    FragK32 w2b[4][2];   // [np][kk]
    #pragma unroll
    for (int np = 0; np < 4; np++)
        #pragma unroll
        for (int kk = 0; kk < 2; kk++) {
            const int n = 16 * np + lm;
            const int k0 = 32 * kk + 4 * q;        // j>>2 == 0 rows
            const int k1 = 32 * kk + 16 + 4 * q;   // j>>2 == 1 rows
            w2b[np][kk].u[0] = pack_pkrtz(W2[(k0 + 0) * NH + n], W2[(k0 + 1) * NH + n]);
            w2b[np][kk].u[1] = pack_pkrtz(W2[(k0 + 2) * NH + n], W2[(k0 + 3) * NH + n]);
            w2b[np][kk].u[2] = pack_pkrtz(W2[(k1 + 0) * NH + n], W2[(k1 + 1) * NH + n]);
            w2b[np][kk].u[3] = pack_pkrtz(W2[(k1 + 2) * NH + n], W2[(k1 + 3) * NH + n]);
        }

    // b2 as layer2 C-init: output rows are planets, cols n'=16np+lm -> broadcast
    f32x4 b2f[4];
    #pragma unroll
    for (int np = 0; np < 4; np++) {
        const float bv = b2[16 * np + lm];
        b2f[np] = (f32x4){bv, bv, bv, bv};
    }

    // batch-invariant planet masses (planet 16*i + lm)
    float pmv[8];
    #pragma unroll
    for (int i = 0; i < 8; i++)
        pmv[i] = planet_m[16 * i + lm];

    const unsigned int bf0_const = q1 ? pack_pkrtz(1.f, 0.f) : 0u;
    const f32x4 zf = (f32x4){0.f, 0.f, 0.f, 0.f};

    // all-ones A-frag for the planet-reduction MFMA
    FragK16 onesA;
    onesA.u[0] = 0x3C003C00u;   // (1.0h, 1.0h)
    onesA.u[1] = 0x3C003C00u;

    // wave-uniform batch base, forced scalar -> SALU addressing below
    int b = __builtin_amdgcn_readfirstlane((blockIdx.x * WPB + wv) * ITERS);

    for (int it = 0; it < ITERS; ++it, ++b) {
        // uniform (SGPR) bases + per-lane constant offsets
        const float* pbase = planet_xy + (size_t)b * (NP * 2);
        const float2 axy = *(const float2*)&ast_xy[2 * b];
        float2 pxy[8];
        #pragma unroll
        for (int i = 0; i < 8; i++)
            pxy[i] = *(const float2*)&pbase[(16 * i + lm) * 2];

        f32x4 redD[4];
        #pragma unroll
        for (int np = 0; np < 4; np++)
            redD[np] = zf;

        #pragma unroll
        for (int mi = 0; mi < 8; ++mi) {
            // feats B-frag for planets 16mi..16mi+15
            float dx = pxy[mi].x - axy.x, dy = pxy[mi].y - axy.y;
            float inv = __builtin_amdgcn_rsqf(fmaf(dx, dx, fmaf(dy, dy, 1e-6f)));
            FragK16 bf;
            bf.u[0] = q0 ? pack_pkrtz(dx, dy)        : bf0_const;
            bf.u[1] = q0 ? pack_pkrtz(inv, pmv[mi])  : 0u;

            // layer1: hT fragments straight into sigma-ordered K32 A-frag slots
            FragK32 hA[2];
            #pragma unroll
            for (int mt = 0; mt < 4; mt++) {
                f32x4 c = __builtin_amdgcn_mfma_f32_16x16x16f16(w1f[mt].v, bf.v, zf, 0, 0, 0);
                hA[mt >> 1].u[2 * (mt & 1) + 0] = relu2_pk(pack_pkrtz(c[0], c[1]));
                hA[mt >> 1].u[2 * (mt & 1) + 1] = relu2_pk(pack_pkrtz(c[2], c[3]));
            }

            // layer2: msg tile [p=4q+r][n'=16np+lm], full-rate K32
            #pragma unroll
            for (int np = 0; np < 4; np++) {
                f32x4 acc = __builtin_amdgcn_mfma_f32_16x16x32_f16(hA[0].v, w2b[np][0].v, b2f[np], 0, 0, 0);
                acc = __builtin_amdgcn_mfma_f32_16x16x32_f16(hA[1].v, w2b[np][1].v, acc, 0, 0, 0);

                // relu + pack to fp16: directly a 16x16x16 B-frag
                FragK16 mf;
                mf.u[0] = relu2_pk(pack_pkrtz(acc[0], acc[1]));
                mf.u[1] = relu2_pk(pack_pkrtz(acc[2], acc[3]));

                // planet reduction on the MFMA pipe: redD += ones @ mf
                redD[np] = __builtin_amdgcn_mfma_f32_16x16x16f16(onesA.v, mf.v, redD[np], 0, 0, 0);
            }
        }

        // lane 16q+lm needs n' = lane -> select np == q; coalesced b32 store
        float v = q0 ? redD[0][0]
                : q1 ? redD[1][0]
                : (q == 2) ? redD[2][0] : redD[3][0];
        out[(size_t)b * NH + lane] = v;
    }
}

extern "C" void kernel_launch(void* const* d_in, const int* in_sizes, int n_in,
                              void* d_out, int out_size, void* d_ws, size_t ws_size,
                              hipStream_t stream) {
    const float* planet_xy = (const float*)d_in[0];
    const float* planet_m  = (const float*)d_in[1];
    const float* ast_xy    = (const float*)d_in[2];
    const float* W1        = (const float*)d_in[3];
    const float* b1        = (const float*)d_in[4];
    const float* W2        = (const float*)d_in[5];
    const float* b2        = (const float*)d_in[6];
    float* outp            = (float*)d_out;

    const int B = in_sizes[2] / 2;   // ast_xy is [B][2]
    const int batches_per_block = WPB * ITERS;
    const int grid = (B + batches_per_block - 1) / batches_per_block;

    gnn_wave<<<grid, 256, 0, stream>>>(planet_xy, planet_m, ast_xy, W1, b1, W2, b2, outp);
}